// Round 8
// baseline (147.932 us; speedup 1.0000x reference)
//
#include <hip/hip_runtime.h>
#include <hip/hip_cooperative_groups.h>
#include <math.h>

namespace cg = cooperative_groups;

#define GAMMA 0.3f      // NUM_BASIS / MAX_RADIUS = 3/10
#define WSTR  1608      // Wlds row stride in bf16 elems (1600 + 8 pad)

typedef __bf16 bf16x8 __attribute__((ext_vector_type(8)));
typedef __bf16 bf16x4 __attribute__((ext_vector_type(4)));
typedef float  f32x4  __attribute__((ext_vector_type(4)));

// ---------------------------------------------------------------------------
// MEGA kernel (cooperative): one launch does everything.
// grid 256 = z(4) x bc(16) x ac(4); 512 threads = 8 waves; 1 block/CU.
// Phase 1 (= proven round-7 k2): per block
//   A: per-lane Gaussian basis registers
//   B: W[b,h,i] = x·rw2 via MFMA -> LDS bf16 [i][k=h*16+b] (8 waves x 25 n-tiles)
//   C: 25 MFMA k-steps per wave (split-K over h-halves), swish A-frag in-register
//   epilogue: combine wk halves via LDS, write part[z,bc,a,i] (16 chunks)
// grid.sync()
// Phase 2: blocks 0..3 (z): sum 16 chunks, abs+mask+pool, normalize (ddof=1),
//   fc3+leaky, fc2 -> out[z]
// MFMA 16x16x32 bf16 frags: A[m=l&15][k=(l>>4)*4+e, +16]; B[k][n=l&15];
//   D col=l&15, row=(l>>4)*4+r   (learn_hip m89-verified)
// ---------------------------------------------------------------------------
__global__ __launch_bounds__(512) void mega(const float* __restrict__ x,
                                            const float* __restrict__ xyz,
                                            const float* __restrict__ rw1,
                                            const float* __restrict__ rw2,
                                            const int*   __restrict__ mask,
                                            const float* __restrict__ fc3_w,
                                            const float* __restrict__ fc3_b,
                                            const float* __restrict__ fc2_w,
                                            const float* __restrict__ fc2_b,
                                            float* __restrict__ part,
                                            float* __restrict__ out) {
    extern __shared__ char smem[];
    __bf16* Wlds = (__bf16*)smem;                          // [32][WSTR]  102,912 B
    float*  rw1s = (float*)(smem + 32 * WSTR * 2);         // [304]         1,216 B
    float (*red)[2][16][17] = (float(*)[2][16][17])(smem + 32 * WSTR * 2 + 1216); // 8,704 B

    int bid = blockIdx.x;
    int ac = bid & 3;
    int bc = (bid >> 2) & 15;
    int z  = bid >> 6;
    int t  = threadIdx.x;
    int w  = t >> 6;              // 0..7
    int wa = w >> 1, wk = w & 1;
    int l  = t & 63;
    int l16 = l & 15, lg = l >> 4;

    for (int e = t; e < 300; e += 512) rw1s[e] = rw1[e];

    // ---- phase A: per-lane bas registers: a-row = l16 (of wa subtile), b = lg*4+e ----
    int a_glob = ac * 64 + wa * 16 + l16;
    float ax = xyz[(z * 256 + a_glob) * 3 + 0];
    float ay = xyz[(z * 256 + a_glob) * 3 + 1];
    float az = xyz[(z * 256 + a_glob) * 3 + 2];
    float bas[4][3];
    #pragma unroll
    for (int e = 0; e < 4; ++e) {
        int b_glob = bc * 16 + lg * 4 + e;
        float dx = xyz[(z * 256 + b_glob) * 3 + 0] - ax;
        float dy = xyz[(z * 256 + b_glob) * 3 + 1] - ay;
        float dz = xyz[(z * 256 + b_glob) * 3 + 2] - az;
        float r  = sqrtf(dx * dx + dy * dy + dz * dz + 1e-12f);
        float r5 = r - 5.f, r10 = r - 10.f;
        bas[e][0] = __expf(-GAMMA * r * r);
        bas[e][1] = __expf(-GAMMA * r5 * r5);
        bas[e][2] = __expf(-GAMMA * r10 * r10);
    }

    // ---- phase B: W chunk via MFMA (M=16 b, N=3200 hi, K=32 j), 25 n-tiles/wave ----
    bf16x8 xa;
    {
        int row = (z * 256 + bc * 16 + l16) * 32;
        float4 v0 = *(const float4*)(x + row + lg * 4);
        float4 v1 = *(const float4*)(x + row + lg * 4 + 16);
        xa[0] = (__bf16)v0.x; xa[1] = (__bf16)v0.y; xa[2] = (__bf16)v0.z; xa[3] = (__bf16)v0.w;
        xa[4] = (__bf16)v1.x; xa[5] = (__bf16)v1.y; xa[6] = (__bf16)v1.z; xa[7] = (__bf16)v1.w;
    }
    for (int q = 0; q < 25; ++q) {
        int nt = w * 25 + q;                 // 0..199
        int h  = nt >> 1;
        int icol = ((nt & 1) << 4) + l16;    // i = 0..31
        const float* rp = rw2 + h * 1024 + icol * 32 + lg * 4;
        float4 r0 = *(const float4*)rp;
        float4 r1 = *(const float4*)(rp + 16);
        bf16x8 rb;
        rb[0] = (__bf16)r0.x; rb[1] = (__bf16)r0.y; rb[2] = (__bf16)r0.z; rb[3] = (__bf16)r0.w;
        rb[4] = (__bf16)r1.x; rb[5] = (__bf16)r1.y; rb[6] = (__bf16)r1.z; rb[7] = (__bf16)r1.w;
        f32x4 d = {0.f, 0.f, 0.f, 0.f};
        d = __builtin_amdgcn_mfma_f32_16x16x32_bf16(xa, rb, d, 0, 0, 0);
        bf16x4 pk;
        pk[0] = (__bf16)d[0]; pk[1] = (__bf16)d[1]; pk[2] = (__bf16)d[2]; pk[3] = (__bf16)d[3];
        *(bf16x4*)&Wlds[icol * WSTR + h * 16 + lg * 4] = pk;
    }
    __syncthreads();

    // ---- phase C: 25 MFMA k-steps over this wave's h-half (k = h*16+b) ----
    f32x4 acc0 = {0.f, 0.f, 0.f, 0.f};
    f32x4 acc1 = {0.f, 0.f, 0.f, 0.f};
    for (int ks = 0; ks < 25; ++ks) {
        int hp = wk * 25 + ks;               // h-pair index 0..49
        int h0 = 2 * hp, h1 = h0 + 1;
        float u00 = rw1s[h0],       u01 = rw1s[h1];
        float u10 = rw1s[100 + h0], u11 = rw1s[100 + h1];
        float u20 = rw1s[200 + h0], u21 = rw1s[200 + h1];
        bf16x8 af;
        #pragma unroll
        for (int e = 0; e < 4; ++e) {
            float p0 = bas[e][0] * u00 + bas[e][1] * u10 + bas[e][2] * u20;
            float p1 = bas[e][0] * u01 + bas[e][1] * u11 + bas[e][2] * u21;
            float s0 = p0 * __builtin_amdgcn_rcpf(1.f + __expf(-p0));   // swish
            float s1 = p1 * __builtin_amdgcn_rcpf(1.f + __expf(-p1));
            af[e]     = (__bf16)s0;    // k = lg*4+e      (h0, even)
            af[e + 4] = (__bf16)s1;    // k = lg*4+e+16   (h1, odd)
        }
        int kb = hp * 32 + lg * 4;
        const __bf16* w0 = &Wlds[l16 * WSTR + kb];
        const __bf16* w1 = w0 + 16 * WSTR;
        bf16x4 b0l = *(const bf16x4*)w0, b0h = *(const bf16x4*)(w0 + 16);
        bf16x4 b1l = *(const bf16x4*)w1, b1h = *(const bf16x4*)(w1 + 16);
        bf16x8 bf0 = __builtin_shufflevector(b0l, b0h, 0, 1, 2, 3, 4, 5, 6, 7);
        bf16x8 bf1 = __builtin_shufflevector(b1l, b1h, 0, 1, 2, 3, 4, 5, 6, 7);
        acc0 = __builtin_amdgcn_mfma_f32_16x16x32_bf16(af, bf0, acc0, 0, 0, 0);
        acc1 = __builtin_amdgcn_mfma_f32_16x16x32_bf16(af, bf1, acc1, 0, 0, 0);
    }

    // ---- epilogue: combine wk halves via LDS, write part (16 chunks) ----
    if (wk == 1) {
        #pragma unroll
        for (int r = 0; r < 4; ++r) {
            red[wa][0][lg * 4 + r][l16] = acc0[r];
            red[wa][1][lg * 4 + r][l16] = acc1[r];
        }
    }
    __syncthreads();
    if (wk == 0) {
        #pragma unroll
        for (int r = 0; r < 4; ++r) {
            float v0 = acc0[r] + red[wa][0][lg * 4 + r][l16];
            float v1 = acc1[r] + red[wa][1][lg * 4 + r][l16];
            int a = ac * 64 + wa * 16 + lg * 4 + r;
            size_t base = ((size_t)(z * 16 + bc) * 256 + a) * 32;
            part[base + l16]      = v0;
            part[base + 16 + l16] = v1;
        }
    }
    __threadfence();                 // release: part visible device-wide (cross-XCD)

    cg::this_grid().sync();

    // ---- phase 2: blocks 0..3 finalize one z each ----
    if (bid < 4) {
        __threadfence();             // acquire side
        int zz = bid;
        float (*pool2)[33] = (float(*)[33])smem;            // [16][33] f32
        float* pn = (float*)(smem + 16 * 33 * 4);           // [32] f32

        int i = t & 31, grp = t >> 5;                       // grp 0..15
        float s = 0.f;
        for (int al = 0; al < 16; ++al) {
            int a = grp * 16 + al;
            float v = 0.f;
            #pragma unroll 4
            for (int q = 0; q < 16; ++q)
                v += part[((size_t)(zz * 16 + q) * 256 + a) * 32 + i];
            float sc = (mask[zz * 256 + a] != 0) ? 0.0625f : 0.f;   // 1/sqrt(256)
            s += fabsf(v) * sc;
        }
        pool2[grp][i] = s;
        __syncthreads();
        if (t < 32) {
            float p = 0.f;
            #pragma unroll
            for (int g = 0; g < 16; ++g) p += pool2[g][t];
            float sm = p;
            #pragma unroll
            for (int off = 16; off; off >>= 1) sm += __shfl_xor(sm, off, 32);
            float mean = sm * (1.f / 32.f);
            float d = p - mean;
            float ss = d * d;
            #pragma unroll
            for (int off = 16; off; off >>= 1) ss += __shfl_xor(ss, off, 32);
            float stdv = sqrtf(ss * (1.f / 31.f));   // ddof=1
            pn[t] = d / (stdv + 1e-6f);
        }
        __syncthreads();
        if (t < 32) {
            float h1 = fc3_b[t];
            #pragma unroll
            for (int j = 0; j < 32; ++j) h1 += pn[j] * fc3_w[j * 32 + t];
            h1 = (h1 >= 0.f) ? h1 : 0.01f * h1;
            float y = h1 * fc2_w[t];
            #pragma unroll
            for (int off = 16; off; off >>= 1) y += __shfl_xor(y, off, 32);
            if (t == 0) out[zz] = y + fc2_b[0];
        }
    }
}

extern "C" void kernel_launch(void* const* d_in, const int* in_sizes, int n_in,
                              void* d_out, int out_size, void* d_ws, size_t ws_size,
                              hipStream_t stream) {
    const float* x    = (const float*)d_in[0];
    const float* xyz  = (const float*)d_in[1];
    const int*   mask = (const int*)d_in[2];
    const float* rw1  = (const float*)d_in[3];
    const float* rw2  = (const float*)d_in[4];
    const float* fc3w = (const float*)d_in[5];
    const float* fc3b = (const float*)d_in[6];
    const float* fc2w = (const float*)d_in[7];
    const float* fc2b = (const float*)d_in[8];
    float* out  = (float*)d_out;
    float* part = (float*)d_ws;      // 4z * 16bc * 256a * 32i * 4B = 2,097,152 B

    const int LDS_BYTES = 32 * WSTR * 2 + 1216 + 8704;      // 112,832

    void* args[] = { (void*)&x, (void*)&xyz, (void*)&rw1, (void*)&rw2, (void*)&mask,
                     (void*)&fc3w, (void*)&fc3b, (void*)&fc2w, (void*)&fc2b,
                     (void*)&part, (void*)&out };
    hipLaunchCooperativeKernel((const void*)mega, dim3(256), dim3(512),
                               args, LDS_BYTES, stream);
}

// Round 9
// 102.373 us; speedup vs baseline: 1.4450x; 1.4450x over previous
//
#include <hip/hip_runtime.h>
#include <math.h>

#define GAMMA 0.3f      // NUM_BASIS / MAX_RADIUS = 3/10
#define WSTR  1608      // Wlds row stride in bf16 elems (1600 + 8 pad; rows 16B-aligned)

typedef __bf16 bf16x8 __attribute__((ext_vector_type(8)));
typedef __bf16 bf16x4 __attribute__((ext_vector_type(4)));
typedef float  f32x4  __attribute__((ext_vector_type(4)));

// ---------------------------------------------------------------------------
// Single fused kernel. grid 256 = z(4) x bc(16) x ac(4); 512 threads = 8 waves.
// Phase 1 (round-7-proven math, round-6-verified kl LDS layout):
//   A: per-lane Gaussian basis registers
//   B: W[b,h,i] = x·rw2 via MFMA -> LDS bf16, kl-packed:
//      Wlds[icol*WSTR + hp*32 + (bl>>2)*8 + (h&1)*4 + (bl&3)]
//      so phase C's B-frag is ONE contiguous ds_read_b128.
//   C: 25 MFMA k-steps per wave (split-K over h-halves), swish A-frag in-register
//   epilogue: combine wk halves via LDS, write part[z,bc,a,i]
// Completion: __threadfence + atomicAdd(cnt[z]); last block (old==63) finalizes:
//   sum 16 chunks, abs+mask+pool, normalize (ddof=1), fc3+leaky, fc2 -> out[z]
// MFMA 16x16x32 bf16 frags: A[m=l&15][k=(l>>4)*4+e, +16]; B[k][n=l&15];
//   D col=l&15, row=(l>>4)*4+r   (learn_hip m89-verified)
// ---------------------------------------------------------------------------
__global__ __launch_bounds__(512) void mega2(const float* __restrict__ x,
                                             const float* __restrict__ xyz,
                                             const float* __restrict__ rw1,
                                             const float* __restrict__ rw2,
                                             const int*   __restrict__ mask,
                                             const float* __restrict__ fc3_w,
                                             const float* __restrict__ fc3_b,
                                             const float* __restrict__ fc2_w,
                                             const float* __restrict__ fc2_b,
                                             float* __restrict__ part,
                                             unsigned* __restrict__ cnt,
                                             float* __restrict__ out) {
    extern __shared__ char smem[];
    __bf16* Wlds = (__bf16*)smem;                          // [32][WSTR]  102,912 B
    float*  rw1s = (float*)(smem + 32 * WSTR * 2);         // [304]         1,216 B
    float (*red)[2][16][17] = (float(*)[2][16][17])(smem + 32 * WSTR * 2 + 1216); // 8,704 B
    __shared__ int isLastS;

    int bid = blockIdx.x;
    int ac = bid & 3;
    int bc = (bid >> 2) & 15;
    int z  = bid >> 6;
    int t  = threadIdx.x;
    int w  = t >> 6;              // 0..7
    int wa = w >> 1, wk = w & 1;
    int l  = t & 63;
    int l16 = l & 15, lg = l >> 4;

    for (int e = t; e < 300; e += 512) rw1s[e] = rw1[e];

    // ---- phase A: per-lane bas registers: a-row = l16 (of wa subtile), b = lg*4+e ----
    int a_glob = ac * 64 + wa * 16 + l16;
    float ax = xyz[(z * 256 + a_glob) * 3 + 0];
    float ay = xyz[(z * 256 + a_glob) * 3 + 1];
    float az = xyz[(z * 256 + a_glob) * 3 + 2];
    float bas[4][3];
    #pragma unroll
    for (int e = 0; e < 4; ++e) {
        int b_glob = bc * 16 + lg * 4 + e;
        float dx = xyz[(z * 256 + b_glob) * 3 + 0] - ax;
        float dy = xyz[(z * 256 + b_glob) * 3 + 1] - ay;
        float dz = xyz[(z * 256 + b_glob) * 3 + 2] - az;
        float r  = sqrtf(dx * dx + dy * dy + dz * dz + 1e-12f);
        float r5 = r - 5.f, r10 = r - 10.f;
        bas[e][0] = __expf(-GAMMA * r * r);
        bas[e][1] = __expf(-GAMMA * r5 * r5);
        bas[e][2] = __expf(-GAMMA * r10 * r10);
    }

    // ---- phase B: W chunk via MFMA (M=16 b, N=3200 hi, K=32 j), 25 n-tiles/wave ----
    bf16x8 xa;
    {
        int row = (z * 256 + bc * 16 + l16) * 32;
        float4 v0 = *(const float4*)(x + row + lg * 4);
        float4 v1 = *(const float4*)(x + row + lg * 4 + 16);
        xa[0] = (__bf16)v0.x; xa[1] = (__bf16)v0.y; xa[2] = (__bf16)v0.z; xa[3] = (__bf16)v0.w;
        xa[4] = (__bf16)v1.x; xa[5] = (__bf16)v1.y; xa[6] = (__bf16)v1.z; xa[7] = (__bf16)v1.w;
    }
    #pragma unroll 2
    for (int q = 0; q < 25; ++q) {
        int nt = w * 25 + q;                 // 0..199
        int h  = nt >> 1;
        int hp = h >> 1, hpar = h & 1;
        int icol = ((nt & 1) << 4) + l16;    // i = 0..31
        const float* rp = rw2 + h * 1024 + icol * 32 + lg * 4;
        float4 r0 = *(const float4*)rp;
        float4 r1 = *(const float4*)(rp + 16);
        bf16x8 rb;
        rb[0] = (__bf16)r0.x; rb[1] = (__bf16)r0.y; rb[2] = (__bf16)r0.z; rb[3] = (__bf16)r0.w;
        rb[4] = (__bf16)r1.x; rb[5] = (__bf16)r1.y; rb[6] = (__bf16)r1.z; rb[7] = (__bf16)r1.w;
        f32x4 d = {0.f, 0.f, 0.f, 0.f};
        d = __builtin_amdgcn_mfma_f32_16x16x32_bf16(xa, rb, d, 0, 0, 0);
        // D reg r <-> bl = lg*4+r ; kl-packed: hp*32 + lg*8 + hpar*4 + r (4 contiguous)
        bf16x4 pk;
        pk[0] = (__bf16)d[0]; pk[1] = (__bf16)d[1]; pk[2] = (__bf16)d[2]; pk[3] = (__bf16)d[3];
        *(bf16x4*)&Wlds[icol * WSTR + hp * 32 + lg * 8 + hpar * 4] = pk;
    }
    __syncthreads();

    // ---- phase C: 25 MFMA k-steps over this wave's h-half; B-frag = 1 ds_read_b128 ----
    f32x4 acc0 = {0.f, 0.f, 0.f, 0.f};
    f32x4 acc1 = {0.f, 0.f, 0.f, 0.f};
    for (int ks = 0; ks < 25; ++ks) {
        int hp = wk * 25 + ks;               // h-pair index 0..49
        int h0 = 2 * hp, h1 = h0 + 1;
        float u00 = rw1s[h0],       u01 = rw1s[h1];
        float u10 = rw1s[100 + h0], u11 = rw1s[100 + h1];
        float u20 = rw1s[200 + h0], u21 = rw1s[200 + h1];
        bf16x8 af;
        #pragma unroll
        for (int e = 0; e < 4; ++e) {
            float p0 = bas[e][0] * u00 + bas[e][1] * u10 + bas[e][2] * u20;
            float p1 = bas[e][0] * u01 + bas[e][1] * u11 + bas[e][2] * u21;
            float s0 = p0 * __builtin_amdgcn_rcpf(1.f + __expf(-p0));   // swish
            float s1 = p1 * __builtin_amdgcn_rcpf(1.f + __expf(-p1));
            af[e]     = (__bf16)s0;    // k = lg*4+e      (h0, even)
            af[e + 4] = (__bf16)s1;    // k = lg*4+e+16   (h1, odd)
        }
        int kb = hp * 32 + lg * 8;
        bf16x8 bf0 = *(const bf16x8*)&Wlds[l16 * WSTR + kb];
        bf16x8 bf1 = *(const bf16x8*)&Wlds[(16 + l16) * WSTR + kb];
        acc0 = __builtin_amdgcn_mfma_f32_16x16x32_bf16(af, bf0, acc0, 0, 0, 0);
        acc1 = __builtin_amdgcn_mfma_f32_16x16x32_bf16(af, bf1, acc1, 0, 0, 0);
    }

    // ---- epilogue: combine wk halves via LDS, write part ----
    if (wk == 1) {
        #pragma unroll
        for (int r = 0; r < 4; ++r) {
            red[wa][0][lg * 4 + r][l16] = acc0[r];
            red[wa][1][lg * 4 + r][l16] = acc1[r];
        }
    }
    __syncthreads();
    if (wk == 0) {
        #pragma unroll
        for (int r = 0; r < 4; ++r) {
            float v0 = acc0[r] + red[wa][0][lg * 4 + r][l16];
            float v1 = acc1[r] + red[wa][1][lg * 4 + r][l16];
            int a = ac * 64 + wa * 16 + lg * 4 + r;
            size_t base = ((size_t)(z * 16 + bc) * 256 + a) * 32;
            part[base + l16]      = v0;
            part[base + 16 + l16] = v1;
        }
    }

    // ---- completion protocol: device-scope release, per-z counter ----
    __threadfence();                 // release: this thread's part writes visible
    __syncthreads();                 // all block threads passed their fence
    if (t == 0) {
        unsigned old = atomicAdd(&cnt[z], 1u);
        isLastS = (old == 63u);
    }
    __syncthreads();
    if (!isLastS) return;
    __threadfence();                 // acquire: invalidate stale cached part lines

    // ---- phase 2 (last block of this z): reduce + normalize + MLP head ----
    float* pool = (float*)smem;                 // [64][33] f32, reuses Wlds space
    float* pn   = (float*)(smem + 64 * 33 * 4); // [32]
    int i4 = (t & 7) * 4;
    int arow = t >> 3;                          // 0..63
    float4 psum = make_float4(0.f, 0.f, 0.f, 0.f);
    for (int ap = 0; ap < 4; ++ap) {
        int a = ap * 64 + arow;
        float4 v = make_float4(0.f, 0.f, 0.f, 0.f);
        #pragma unroll 4
        for (int q = 0; q < 16; ++q) {
            const float* p = &part[((size_t)(z * 16 + q) * 256 + a) * 32 + i4];
            v.x += p[0]; v.y += p[1]; v.z += p[2]; v.w += p[3];
        }
        float sc = (mask[z * 256 + a] != 0) ? 0.0625f : 0.f;   // 1/sqrt(256)
        psum.x += fabsf(v.x) * sc; psum.y += fabsf(v.y) * sc;
        psum.z += fabsf(v.z) * sc; psum.w += fabsf(v.w) * sc;
    }
    pool[arow * 33 + i4 + 0] = psum.x;
    pool[arow * 33 + i4 + 1] = psum.y;
    pool[arow * 33 + i4 + 2] = psum.z;
    pool[arow * 33 + i4 + 3] = psum.w;
    __syncthreads();
    if (t < 32) {
        float p = 0.f;
        #pragma unroll
        for (int r = 0; r < 64; ++r) p += pool[r * 33 + t];
        float sm = p;
        #pragma unroll
        for (int off = 16; off; off >>= 1) sm += __shfl_xor(sm, off, 32);
        float mean = sm * (1.f / 32.f);
        float d = p - mean;
        float ss = d * d;
        #pragma unroll
        for (int off = 16; off; off >>= 1) ss += __shfl_xor(ss, off, 32);
        float stdv = sqrtf(ss * (1.f / 31.f));   // ddof=1
        pn[t] = d / (stdv + 1e-6f);
    }
    __syncthreads();
    if (t < 32) {
        float h1 = fc3_b[t];
        #pragma unroll
        for (int j = 0; j < 32; ++j) h1 += pn[j] * fc3_w[j * 32 + t];
        h1 = (h1 >= 0.f) ? h1 : 0.01f * h1;
        float y = h1 * fc2_w[t];
        #pragma unroll
        for (int off = 16; off; off >>= 1) y += __shfl_xor(y, off, 32);
        if (t == 0) out[z] = y + fc2_b[0];
    }
}

extern "C" void kernel_launch(void* const* d_in, const int* in_sizes, int n_in,
                              void* d_out, int out_size, void* d_ws, size_t ws_size,
                              hipStream_t stream) {
    const float* x    = (const float*)d_in[0];
    const float* xyz  = (const float*)d_in[1];
    const int*   mask = (const int*)d_in[2];
    const float* rw1  = (const float*)d_in[3];
    const float* rw2  = (const float*)d_in[4];
    const float* fc3w = (const float*)d_in[5];
    const float* fc3b = (const float*)d_in[6];
    const float* fc2w = (const float*)d_in[7];
    const float* fc2b = (const float*)d_in[8];
    float* out  = (float*)d_out;

    float*    part = (float*)d_ws;                        // 4*16*256*32*4 = 2,097,152 B
    unsigned* cnt  = (unsigned*)((char*)d_ws + 2097152);  // 16 B

    const int LDS_BYTES = 32 * WSTR * 2 + 1216 + 8704;    // 112,832

    hipMemsetAsync(cnt, 0, 16, stream);                   // graph-capturable memset node
    hipLaunchKernelGGL(mega2, dim3(256), dim3(512), LDS_BYTES, stream,
                       x, xyz, rw1, rw2, mask, fc3w, fc3b, fc2w, fc2b, part, cnt, out);
}

// Round 10
// 53.734 us; speedup vs baseline: 2.7531x; 1.9052x over previous
//
#include <hip/hip_runtime.h>
#include <math.h>

#define GAMMA 0.3f      // NUM_BASIS / MAX_RADIUS = 3/10
#define WSTR2 808       // k2 LDS row stride in bf16 (800 + 8 pad; rows 16B-aligned)

typedef __bf16 bf16x8 __attribute__((ext_vector_type(8)));
typedef __bf16 bf16x4 __attribute__((ext_vector_type(4)));
typedef float  f32x4  __attribute__((ext_vector_type(4)));

// ---------------------------------------------------------------------------
// K2: grid 256 = z(4) x bc(16) x hh(2) x ah(2); 512 threads = 8 waves.
// Block: a in [ah*128,+128), b in [bc*16,+16), h in [hh*50,+50); K = 800.
// Phase B: W[b,h,i] = x·rw2 via MFMA -> LDS bf16 kl-packed (r9-validated):
//   Wlds[icol*WSTR2 + hp_loc*32 + lg*8 + hpar*4 + r]
// Phase C: wave w owns a-tile w; 25 k-steps x 2 i-tiles; B-frag = 1 ds_read_b128.
// No split-K epilogue: acc is the final partial for chunk qc = bc*2+hh.
// MFMA 16x16x32 bf16 frags: A[m=l&15][k=(l>>4)*4+e, +16]; B[k][n=l&15];
//   D col=l&15, row=(l>>4)*4+r   (learn_hip m89-verified)
// ---------------------------------------------------------------------------
__global__ __launch_bounds__(512) void k2_fused(const float* __restrict__ x,
                                                const float* __restrict__ xyz,
                                                const float* __restrict__ rw1,
                                                const float* __restrict__ rw2,
                                                float* __restrict__ part) {
    extern __shared__ char smem[];
    __bf16* Wlds = (__bf16*)smem;                      // [32][WSTR2]  51,712 B
    float*  rw1s = (float*)(smem + 32 * WSTR2 * 2);    // [304]         1,216 B

    int bid = blockIdx.x;
    int ah = bid & 1;
    int hh = (bid >> 1) & 1;
    int bc = (bid >> 2) & 15;
    int z  = bid >> 6;
    int t  = threadIdx.x;
    int w  = t >> 6;              // 0..7 = a-tile
    int l  = t & 63;
    int l16 = l & 15, lg = l >> 4;

    for (int e = t; e < 300; e += 512) rw1s[e] = rw1[e];

    // ---- phase A: per-lane bas registers: a = l16 of wave's a-tile, b = lg*4+e ----
    int a_glob = ah * 128 + w * 16 + l16;
    float ax = xyz[(z * 256 + a_glob) * 3 + 0];
    float ay = xyz[(z * 256 + a_glob) * 3 + 1];
    float az = xyz[(z * 256 + a_glob) * 3 + 2];
    float bas[4][3];
    #pragma unroll
    for (int e = 0; e < 4; ++e) {
        int b_glob = bc * 16 + lg * 4 + e;
        float dx = xyz[(z * 256 + b_glob) * 3 + 0] - ax;
        float dy = xyz[(z * 256 + b_glob) * 3 + 1] - ay;
        float dz = xyz[(z * 256 + b_glob) * 3 + 2] - az;
        float r  = sqrtf(dx * dx + dy * dy + dz * dz + 1e-12f);
        float r5 = r - 5.f, r10 = r - 10.f;
        bas[e][0] = __expf(-GAMMA * r * r);
        bas[e][1] = __expf(-GAMMA * r5 * r5);
        bas[e][2] = __expf(-GAMMA * r10 * r10);
    }

    // ---- phase B: W h-half via MFMA; 100 n-tiles over 8 waves ----
    bf16x8 xa;
    {
        int row = (z * 256 + bc * 16 + l16) * 32;
        float4 v0 = *(const float4*)(x + row + lg * 4);
        float4 v1 = *(const float4*)(x + row + lg * 4 + 16);
        xa[0] = (__bf16)v0.x; xa[1] = (__bf16)v0.y; xa[2] = (__bf16)v0.z; xa[3] = (__bf16)v0.w;
        xa[4] = (__bf16)v1.x; xa[5] = (__bf16)v1.y; xa[6] = (__bf16)v1.z; xa[7] = (__bf16)v1.w;
    }
    for (int q = 0; q < 13; ++q) {
        int nt = q * 8 + w;                  // 0..103; valid < 100
        if (nt < 100) {
            int h_loc = nt >> 1;             // 0..49
            int h = hh * 50 + h_loc;
            int hp_loc = h_loc >> 1, hpar = h_loc & 1;
            int icol = ((nt & 1) << 4) + l16;
            const float* rp = rw2 + h * 1024 + icol * 32 + lg * 4;
            float4 r0 = *(const float4*)rp;
            float4 r1 = *(const float4*)(rp + 16);
            bf16x8 rb;
            rb[0] = (__bf16)r0.x; rb[1] = (__bf16)r0.y; rb[2] = (__bf16)r0.z; rb[3] = (__bf16)r0.w;
            rb[4] = (__bf16)r1.x; rb[5] = (__bf16)r1.y; rb[6] = (__bf16)r1.z; rb[7] = (__bf16)r1.w;
            f32x4 d = {0.f, 0.f, 0.f, 0.f};
            d = __builtin_amdgcn_mfma_f32_16x16x32_bf16(xa, rb, d, 0, 0, 0);
            bf16x4 pk;
            pk[0] = (__bf16)d[0]; pk[1] = (__bf16)d[1]; pk[2] = (__bf16)d[2]; pk[3] = (__bf16)d[3];
            *(bf16x4*)&Wlds[icol * WSTR2 + hp_loc * 32 + lg * 8 + hpar * 4] = pk;
        }
    }
    __syncthreads();

    // ---- phase C: 25 k-steps (k = 2h x 16b), B-frag = 1 ds_read_b128 per i-tile ----
    f32x4 acc0 = {0.f, 0.f, 0.f, 0.f};
    f32x4 acc1 = {0.f, 0.f, 0.f, 0.f};
    for (int ks = 0; ks < 25; ++ks) {
        int h0 = hh * 50 + 2 * ks;
        float2 u0 = *(const float2*)&rw1s[h0];          // rw1[0][h0], rw1[0][h1]
        float2 u1 = *(const float2*)&rw1s[100 + h0];
        float2 u2 = *(const float2*)&rw1s[200 + h0];
        bf16x8 af;
        #pragma unroll
        for (int e = 0; e < 4; ++e) {
            float p0 = bas[e][0] * u0.x + bas[e][1] * u1.x + bas[e][2] * u2.x;
            float p1 = bas[e][0] * u0.y + bas[e][1] * u1.y + bas[e][2] * u2.y;
            float s0 = p0 * __builtin_amdgcn_rcpf(1.f + __expf(-p0));   // swish
            float s1 = p1 * __builtin_amdgcn_rcpf(1.f + __expf(-p1));
            af[e]     = (__bf16)s0;    // k = lg*4+e      (h0, even)
            af[e + 4] = (__bf16)s1;    // k = lg*4+e+16   (h1, odd)
        }
        int kb = ks * 32 + lg * 8;
        bf16x8 bf0 = *(const bf16x8*)&Wlds[l16 * WSTR2 + kb];
        bf16x8 bf1 = *(const bf16x8*)&Wlds[(16 + l16) * WSTR2 + kb];
        acc0 = __builtin_amdgcn_mfma_f32_16x16x32_bf16(af, bf0, acc0, 0, 0, 0);
        acc1 = __builtin_amdgcn_mfma_f32_16x16x32_bf16(af, bf1, acc1, 0, 0, 0);
    }

    // ---- write partials: chunk qc = bc*2+hh; D row r -> a = atile + lg*4+r ----
    int qc = bc * 2 + hh;
    #pragma unroll
    for (int r = 0; r < 4; ++r) {
        int a = ah * 128 + w * 16 + lg * 4 + r;
        size_t base = ((size_t)(z * 32 + qc) * 256 + a) * 32;
        part[base + l16]      = acc0[r];
        part[base + 16 + l16] = acc1[r];
    }
}

// ---------------------------------------------------------------------------
// K3: sum over 32 chunks, abs+mask+scale, pool 4 a's per block; last block of
// each z (cnt protocol, r9-validated) finalizes: normalize (ddof=1) + fc3 +
// leaky + fc2 -> out[z].
// grid: 256 blocks = z(4) x ag(64); 256 threads = a_loc(4) x qg(2) x i(32)
// ---------------------------------------------------------------------------
__global__ __launch_bounds__(256) void k3_fused(const float* __restrict__ part,
                                                const int* __restrict__ mask,
                                                const float* __restrict__ fc3_w,
                                                const float* __restrict__ fc3_b,
                                                const float* __restrict__ fc2_w,
                                                const float* __restrict__ fc2_b,
                                                float* __restrict__ pooled_part,
                                                unsigned* __restrict__ cnt,
                                                float* __restrict__ out) {
    __shared__ float buf[4][2][32];
    __shared__ float pn[32];
    __shared__ int isLastS;
    int blk = blockIdx.x;
    int z = blk >> 6, ag = blk & 63;
    int t = threadIdx.x;
    int i = t & 31;
    int qg = (t >> 5) & 1;
    int a_loc = t >> 6;               // 0..3
    int a = ag * 4 + a_loc;
    const float* base = part + ((size_t)z * 32 * 256 + (size_t)a) * 32 + i;
    float s = 0.f;
    for (int q = qg; q < 32; q += 2)
        s += base[(size_t)q * 8192];
    buf[a_loc][qg][i] = s;
    __syncthreads();
    if (t < 128) {
        int al = t >> 5, ii = t & 31;
        float v = buf[al][0][ii] + buf[al][1][ii];
        float sc = (mask[z * 256 + ag * 4 + al] != 0) ? 0.0625f : 0.f;   // 1/sqrt(256)
        buf[al][0][ii] = fabsf(v) * sc;
    }
    __syncthreads();
    if (t < 32) {
        float v = buf[0][0][t] + buf[1][0][t] + buf[2][0][t] + buf[3][0][t];
        pooled_part[(z * 64 + ag) * 32 + t] = v;
    }

    // ---- completion: device-scope release + per-z counter (r9-validated) ----
    __threadfence();
    __syncthreads();
    if (t == 0) {
        unsigned old = atomicAdd(&cnt[z], 1u);
        isLastS = (old == 63u);
    }
    __syncthreads();
    if (!isLastS) return;
    __threadfence();                 // acquire

    // ---- tail (8 KB read): pool over ag, normalize, fc3+leaky, fc2 ----
    if (t < 32) {
        float p = 0.f;
        for (int g = 0; g < 64; ++g) p += pooled_part[(z * 64 + g) * 32 + t];
        float sm = p;
        #pragma unroll
        for (int off = 16; off; off >>= 1) sm += __shfl_xor(sm, off, 32);
        float mean = sm * (1.f / 32.f);
        float d = p - mean;
        float ss = d * d;
        #pragma unroll
        for (int off = 16; off; off >>= 1) ss += __shfl_xor(ss, off, 32);
        float stdv = sqrtf(ss * (1.f / 31.f));   // ddof=1
        pn[t] = d / (stdv + 1e-6f);
    }
    __syncthreads();
    if (t < 32) {
        float h1 = fc3_b[t];
        #pragma unroll
        for (int j = 0; j < 32; ++j) h1 += pn[j] * fc3_w[j * 32 + t];
        h1 = (h1 >= 0.f) ? h1 : 0.01f * h1;
        float y = h1 * fc2_w[t];
        #pragma unroll
        for (int off = 16; off; off >>= 1) y += __shfl_xor(y, off, 32);
        if (t == 0) out[z] = y + fc2_b[0];
    }
}

extern "C" void kernel_launch(void* const* d_in, const int* in_sizes, int n_in,
                              void* d_out, int out_size, void* d_ws, size_t ws_size,
                              hipStream_t stream) {
    const float* x    = (const float*)d_in[0];
    const float* xyz  = (const float*)d_in[1];
    const int*   mask = (const int*)d_in[2];
    const float* rw1  = (const float*)d_in[3];
    const float* rw2  = (const float*)d_in[4];
    const float* fc3w = (const float*)d_in[5];
    const float* fc3b = (const float*)d_in[6];
    const float* fc2w = (const float*)d_in[7];
    const float* fc2b = (const float*)d_in[8];
    float* out = (float*)d_out;

    float*    part        = (float*)d_ws;                        // 4*32*256*32*4 = 4,194,304 B
    float*    pooled_part = (float*)((char*)d_ws + 4194304);     // 32,768 B
    unsigned* cnt         = (unsigned*)((char*)d_ws + 4227072);  // 16 B

    const int LDS_BYTES = 32 * WSTR2 * 2 + 1216;   // 51,712 + 1,216 = 52,928

    hipMemsetAsync(cnt, 0, 16, stream);
    hipLaunchKernelGGL(k2_fused, dim3(256), dim3(512), LDS_BYTES, stream,
                       x, xyz, rw1, rw2, part);
    hipLaunchKernelGGL(k3_fused, dim3(256), dim3(256), 0, stream,
                       part, mask, fc3w, fc3b, fc2w, fc2b, pooled_part, cnt, out);
}

// Round 11
// 35.868 us; speedup vs baseline: 4.1244x; 1.4981x over previous
//
#include <hip/hip_runtime.h>
#include <math.h>

#define GAMMA 0.3f      // NUM_BASIS / MAX_RADIUS = 3/10
#define WSTR2 808       // k2 LDS row stride in bf16 (800 + 8 pad; rows 16B-aligned)

typedef __bf16 bf16x8 __attribute__((ext_vector_type(8)));
typedef __bf16 bf16x4 __attribute__((ext_vector_type(4)));
typedef float  f32x4  __attribute__((ext_vector_type(4)));

// ---------------------------------------------------------------------------
// K2 (round-10 version, correctness-proven): grid 256 = z(4) x bc(16) x hh(2)
// x ah(2); 512 threads = 8 waves.
// Block: a in [ah*128,+128), b in [bc*16,+16), h in [hh*50,+50); K = 800.
// Phase B: W[b,h,i] = x·rw2 via MFMA -> LDS bf16 kl-packed:
//   Wlds[icol*WSTR2 + hp_loc*32 + lg*8 + hpar*4 + r]  (B-frag = 1 ds_read_b128)
// Phase C: wave w owns a-tile w; 25 k-steps x 2 i-tiles; no split-K epilogue.
// MFMA 16x16x32 bf16 frags: A[m=l&15][k=(l>>4)*4+e, +16]; B[k][n=l&15];
//   D col=l&15, row=(l>>4)*4+r   (learn_hip m89-verified)
// ---------------------------------------------------------------------------
__global__ __launch_bounds__(512) void k2_fused(const float* __restrict__ x,
                                                const float* __restrict__ xyz,
                                                const float* __restrict__ rw1,
                                                const float* __restrict__ rw2,
                                                float* __restrict__ part) {
    extern __shared__ char smem[];
    __bf16* Wlds = (__bf16*)smem;                      // [32][WSTR2]  51,712 B
    float*  rw1s = (float*)(smem + 32 * WSTR2 * 2);    // [304]         1,216 B

    int bid = blockIdx.x;
    int ah = bid & 1;
    int hh = (bid >> 1) & 1;
    int bc = (bid >> 2) & 15;
    int z  = bid >> 6;
    int t  = threadIdx.x;
    int w  = t >> 6;              // 0..7 = a-tile
    int l  = t & 63;
    int l16 = l & 15, lg = l >> 4;

    for (int e = t; e < 300; e += 512) rw1s[e] = rw1[e];

    // ---- phase A: per-lane bas registers: a = l16 of wave's a-tile, b = lg*4+e ----
    int a_glob = ah * 128 + w * 16 + l16;
    float ax = xyz[(z * 256 + a_glob) * 3 + 0];
    float ay = xyz[(z * 256 + a_glob) * 3 + 1];
    float az = xyz[(z * 256 + a_glob) * 3 + 2];
    float bas[4][3];
    #pragma unroll
    for (int e = 0; e < 4; ++e) {
        int b_glob = bc * 16 + lg * 4 + e;
        float dx = xyz[(z * 256 + b_glob) * 3 + 0] - ax;
        float dy = xyz[(z * 256 + b_glob) * 3 + 1] - ay;
        float dz = xyz[(z * 256 + b_glob) * 3 + 2] - az;
        float r  = sqrtf(dx * dx + dy * dy + dz * dz + 1e-12f);
        float r5 = r - 5.f, r10 = r - 10.f;
        bas[e][0] = __expf(-GAMMA * r * r);
        bas[e][1] = __expf(-GAMMA * r5 * r5);
        bas[e][2] = __expf(-GAMMA * r10 * r10);
    }

    // ---- phase B: W h-half via MFMA; 100 n-tiles over 8 waves ----
    bf16x8 xa;
    {
        int row = (z * 256 + bc * 16 + l16) * 32;
        float4 v0 = *(const float4*)(x + row + lg * 4);
        float4 v1 = *(const float4*)(x + row + lg * 4 + 16);
        xa[0] = (__bf16)v0.x; xa[1] = (__bf16)v0.y; xa[2] = (__bf16)v0.z; xa[3] = (__bf16)v0.w;
        xa[4] = (__bf16)v1.x; xa[5] = (__bf16)v1.y; xa[6] = (__bf16)v1.z; xa[7] = (__bf16)v1.w;
    }
    for (int q = 0; q < 13; ++q) {
        int nt = q * 8 + w;                  // 0..103; valid < 100
        if (nt < 100) {
            int h_loc = nt >> 1;             // 0..49
            int h = hh * 50 + h_loc;
            int hp_loc = h_loc >> 1, hpar = h_loc & 1;
            int icol = ((nt & 1) << 4) + l16;
            const float* rp = rw2 + h * 1024 + icol * 32 + lg * 4;
            float4 r0 = *(const float4*)rp;
            float4 r1 = *(const float4*)(rp + 16);
            bf16x8 rb;
            rb[0] = (__bf16)r0.x; rb[1] = (__bf16)r0.y; rb[2] = (__bf16)r0.z; rb[3] = (__bf16)r0.w;
            rb[4] = (__bf16)r1.x; rb[5] = (__bf16)r1.y; rb[6] = (__bf16)r1.z; rb[7] = (__bf16)r1.w;
            f32x4 d = {0.f, 0.f, 0.f, 0.f};
            d = __builtin_amdgcn_mfma_f32_16x16x32_bf16(xa, rb, d, 0, 0, 0);
            bf16x4 pk;
            pk[0] = (__bf16)d[0]; pk[1] = (__bf16)d[1]; pk[2] = (__bf16)d[2]; pk[3] = (__bf16)d[3];
            *(bf16x4*)&Wlds[icol * WSTR2 + hp_loc * 32 + lg * 8 + hpar * 4] = pk;
        }
    }
    __syncthreads();

    // ---- phase C: 25 k-steps (k = 2h x 16b), B-frag = 1 ds_read_b128 per i-tile ----
    f32x4 acc0 = {0.f, 0.f, 0.f, 0.f};
    f32x4 acc1 = {0.f, 0.f, 0.f, 0.f};
    for (int ks = 0; ks < 25; ++ks) {
        int h0 = hh * 50 + 2 * ks;
        float2 u0 = *(const float2*)&rw1s[h0];
        float2 u1 = *(const float2*)&rw1s[100 + h0];
        float2 u2 = *(const float2*)&rw1s[200 + h0];
        bf16x8 af;
        #pragma unroll
        for (int e = 0; e < 4; ++e) {
            float p0 = bas[e][0] * u0.x + bas[e][1] * u1.x + bas[e][2] * u2.x;
            float p1 = bas[e][0] * u0.y + bas[e][1] * u1.y + bas[e][2] * u2.y;
            float s0 = p0 * __builtin_amdgcn_rcpf(1.f + __expf(-p0));   // swish
            float s1 = p1 * __builtin_amdgcn_rcpf(1.f + __expf(-p1));
            af[e]     = (__bf16)s0;    // k = lg*4+e      (h0, even)
            af[e + 4] = (__bf16)s1;    // k = lg*4+e+16   (h1, odd)
        }
        int kb = ks * 32 + lg * 8;
        bf16x8 bf0 = *(const bf16x8*)&Wlds[l16 * WSTR2 + kb];
        bf16x8 bf1 = *(const bf16x8*)&Wlds[(16 + l16) * WSTR2 + kb];
        acc0 = __builtin_amdgcn_mfma_f32_16x16x32_bf16(af, bf0, acc0, 0, 0, 0);
        acc1 = __builtin_amdgcn_mfma_f32_16x16x32_bf16(af, bf1, acc1, 0, 0, 0);
    }

    // ---- write partials: chunk qc = bc*2+hh; D row r -> a = atile + lg*4+r ----
    int qc = bc * 2 + hh;
    #pragma unroll
    for (int r = 0; r < 4; ++r) {
        int a = ah * 128 + w * 16 + lg * 4 + r;
        size_t base = ((size_t)(z * 32 + qc) * 256 + a) * 32;
        part[base + l16]      = acc0[r];
        part[base + 16 + l16] = acc1[r];
    }
}

// ---------------------------------------------------------------------------
// K3: one block per z (grid 4, 1024 threads = 16 waves). Fence-free:
// kernel-boundary coherence only. Reads part[z] (1 MB) with coalesced
// float4 loads, sums 32 chunks, abs+mask+scale, pools over a in LDS,
// normalizes (ddof=1), fc3+leaky, fc2 -> out[z].
// ---------------------------------------------------------------------------
__global__ __launch_bounds__(1024) void k3_final(const float* __restrict__ part,
                                                 const int* __restrict__ mask,
                                                 const float* __restrict__ fc3_w,
                                                 const float* __restrict__ fc3_b,
                                                 const float* __restrict__ fc2_w,
                                                 const float* __restrict__ fc2_b,
                                                 float* __restrict__ out) {
    __shared__ float pool[128][36];
    __shared__ float pool2[8][33];
    __shared__ float pn[32];
    int z = blockIdx.x;
    int t = threadIdx.x;
    int c4 = t & 7;                 // float4 column (i = c4*4 .. +3)
    int al = t >> 3;                // 0..127
    const float4* p4 = (const float4*)part;

    float4 acc = make_float4(0.f, 0.f, 0.f, 0.f);
    #pragma unroll
    for (int ap = 0; ap < 2; ++ap) {
        int a = ap * 128 + al;
        size_t base = ((size_t)(z * 32) * 256 + a) * 8 + c4;
        float4 v = make_float4(0.f, 0.f, 0.f, 0.f);
        #pragma unroll 4
        for (int q = 0; q < 32; ++q) {
            float4 u = p4[base + (size_t)q * 2048];
            v.x += u.x; v.y += u.y; v.z += u.z; v.w += u.w;
        }
        float sc = (mask[z * 256 + a] != 0) ? 0.0625f : 0.f;   // 1/sqrt(256)
        acc.x += fabsf(v.x) * sc; acc.y += fabsf(v.y) * sc;
        acc.z += fabsf(v.z) * sc; acc.w += fabsf(v.w) * sc;
    }
    pool[al][c4 * 4 + 0] = acc.x;
    pool[al][c4 * 4 + 1] = acc.y;
    pool[al][c4 * 4 + 2] = acc.z;
    pool[al][c4 * 4 + 3] = acc.w;
    __syncthreads();
    if (t < 256) {
        int ii = t & 31, rg = t >> 5;       // rg 0..7
        float s = 0.f;
        #pragma unroll
        for (int r = 0; r < 16; ++r) s += pool[rg + r * 8][ii];
        pool2[rg][ii] = s;
    }
    __syncthreads();
    if (t < 32) {
        float p = 0.f;
        #pragma unroll
        for (int g = 0; g < 8; ++g) p += pool2[g][t];
        float sm = p;
        #pragma unroll
        for (int off = 16; off; off >>= 1) sm += __shfl_xor(sm, off, 32);
        float mean = sm * (1.f / 32.f);
        float d = p - mean;
        float ss = d * d;
        #pragma unroll
        for (int off = 16; off; off >>= 1) ss += __shfl_xor(ss, off, 32);
        float stdv = sqrtf(ss * (1.f / 31.f));   // ddof=1
        pn[t] = d / (stdv + 1e-6f);
    }
    __syncthreads();
    if (t < 32) {
        float h1 = fc3_b[t];
        #pragma unroll
        for (int j = 0; j < 32; ++j) h1 += pn[j] * fc3_w[j * 32 + t];
        h1 = (h1 >= 0.f) ? h1 : 0.01f * h1;
        float y = h1 * fc2_w[t];
        #pragma unroll
        for (int off = 16; off; off >>= 1) y += __shfl_xor(y, off, 32);
        if (t == 0) out[z] = y + fc2_b[0];
    }
}

extern "C" void kernel_launch(void* const* d_in, const int* in_sizes, int n_in,
                              void* d_out, int out_size, void* d_ws, size_t ws_size,
                              hipStream_t stream) {
    const float* x    = (const float*)d_in[0];
    const float* xyz  = (const float*)d_in[1];
    const int*   mask = (const int*)d_in[2];
    const float* rw1  = (const float*)d_in[3];
    const float* rw2  = (const float*)d_in[4];
    const float* fc3w = (const float*)d_in[5];
    const float* fc3b = (const float*)d_in[6];
    const float* fc2w = (const float*)d_in[7];
    const float* fc2b = (const float*)d_in[8];
    float* out = (float*)d_out;

    float* part = (float*)d_ws;     // 4z * 32qc * 256a * 32i * 4B = 4,194,304 B

    const int LDS_BYTES = 32 * WSTR2 * 2 + 1216;   // 52,928

    hipLaunchKernelGGL(k2_fused, dim3(256), dim3(512), LDS_BYTES, stream,
                       x, xyz, rw1, rw2, part);
    hipLaunchKernelGGL(k3_final, dim3(4), dim3(1024), 0, stream,
                       part, mask, fc3w, fc3b, fc2w, fc2b, out);
}